// Round 7
// baseline (250.406 us; speedup 1.0000x reference)
//
#include <hip/hip_runtime.h>
#include <math.h>

// SpecNorm: x[B,T,F,2] fp32 -> x * rsqrt(ema(|x|) + eps)
// EMA sequential in T; lookback reconstructs state (0.9^128 ~= 1.4e-6 rel
// error; threshold 0.129, measured absmax 0.0156 at LOOKBACK=128).
//
// R11: R10 post-mortem -- byte-minimal confirmed (FETCH 118 MB == input,
// WRITE 124.7 MB == output) and 2.65 TB/s invariant across MLP 1->8,
// NT->cached, 4->16 waves/CU (R5..R10). One counter says the ceiling is
// CU-side, not DRAM-side: per-CU issued bytes rose 6.3 -> 7.4 B/cyc going
// 4 -> 16 waves/CU (R10 vs R9); R9 only lost wall-time to 3x warmup
// redundancy. This round: more waves/CU at byte-minimal geometry by
// halving bytes/lane -- one complex (8 B) per thread, 512-thread blocks
// (8 waves/CU, grid unchanged 256 blocks = 1/CU). 481 threads cover a row
// EXACTLY: the tid==240 split store, divergent path, and end-of-buffer
// over-read all disappear; per-thread state halves. asm load + counted
// vmcnt pipeline carried verbatim (8 loads / 8 stores per batch).
// Discriminator: win => ~70-80 us; flat => pattern ceiling proven, bytes
// minimal, declare roofline.

#define ALPHA 0.9f
#define OMA   0.1f
#define EPS_  1e-12f

typedef float vf2 __attribute__((ext_vector_type(2), aligned(8)));

constexpr int B_ = 16, T_ = 2000, F_ = 481;
constexpr int NCH = 16, LOOKBACK = 128;
constexpr int OUT0 = 200, OUTN = 120;   // 200 + 15*120 = 2000; both %8 == 0
constexpr int ROWF = 2 * F_;            // 962 floats per row (3848 B)

#define SB() __builtin_amdgcn_sched_barrier(0)
// Counted wait: N youngest vmem ops may remain outstanding. sched_barrier
// right after so dependent VALU can't be hoisted past it (rule #18).
#define WAITV(N) do { \
  asm volatile("s_waitcnt vmcnt(" #N ")" ::: "memory"); SB(); \
} while (0)

// Two rows from one pointer: row stride 3848 B fits the 13-bit signed imm.
// "=&v" earlyclobber: dest must not alias the addr pair.
#define ALD2(d0, d1, p) \
  asm volatile("global_load_dwordx2 %0, %2, off\n\t" \
               "global_load_dwordx2 %1, %2, off offset:3848" \
               : "=&v"(d0), "=&v"(d1) : "v"(p))

// 8-row batch: 8 loads issued back-to-back (MLP 8), pointers advance 8 rows.
#define ALD8(V) do { \
  ALD2(V##0, V##1, p0); ALD2(V##2, V##3, p1); \
  ALD2(V##4, V##5, p2); ALD2(V##6, V##7, p3); \
  p0 += 8 * ROWF; p1 += 8 * ROWF; p2 += 8 * ROWF; p3 += 8 * ROWF; \
} while (0)

// One channel per thread: EMA on |x| of this thread's complex.
#define EMA1(v) do { \
  float aA = __builtin_amdgcn_sqrtf((v).x * (v).x + (v).y * (v).y); \
  sA = ALPHA * sA + OMA * aA; \
} while (0)

#define EMA8(V) do { EMA1(V##0); EMA1(V##1); EMA1(V##2); EMA1(V##3); \
                     EMA1(V##4); EMA1(V##5); EMA1(V##6); EMA1(V##7); } while (0)

// One output row: EMA update, rsqrt, one uniform 8 B store (no divergence:
// 481 threads cover the 3848 B row exactly).
#define OUT1(v) do { \
  EMA1(v); \
  float iA = __builtin_amdgcn_rsqf(sA + EPS_); \
  vf2 o = { (v).x * iA, (v).y * iA }; \
  asm volatile("global_store_dwordx2 %0, %1, off" :: "v"(op), "v"(o)); \
  op += ROWF; \
} while (0)

#define OUT8(V) do { OUT1(V##0); OUT1(V##1); OUT1(V##2); OUT1(V##3); \
                     OUT1(V##4); OUT1(V##5); OUT1(V##6); OUT1(V##7); } while (0)

__global__ __launch_bounds__(512, 1)
void specnorm_kernel(const float* __restrict__ x, float* __restrict__ out,
                     float* __restrict__ ws) {
    const int tid = threadIdx.x;
    if (tid >= F_) return;              // 481..511 idle (wave 7 half-active)
    const int chunk = blockIdx.x;
    const int b = blockIdx.y;

    // s0[f] = 0.001 + f*step
    const float step = (float)((0.0001 - 0.001) / (double)(F_ - 1));
    float sA = 0.001f + (float)tid * step;

    const int tout0 = (chunk == 0) ? 0 : OUT0 + (chunk - 1) * OUTN;
    const int nb    = (chunk == 0) ? (OUT0 / 8) : (OUTN / 8);  // 25 or 15
    const int nwarm = (chunk == 0) ? 0 : LOOKBACK;
    const int tstart = tout0 - nwarm;   // >= 72 for chunk >= 1 (OUT0>=LOOKBACK)

    // All accesses 8 B, 8 B-aligned, exactly in-bounds (481 thr x 8 B = row).
    const float* base = x + (size_t)(b * T_ + tstart) * ROWF + 2 * tid;
    const float* p0 = base;
    const float* p1 = base + 2 * ROWF;
    const float* p2 = base + 4 * ROWF;
    const float* p3 = base + 6 * ROWF;
    float* op = out + (size_t)(b * T_ + tout0) * ROWF + 2 * tid;
    (void)ws;

    vf2 a0, a1, a2, a3, a4, a5, a6, a7;
    vf2 b0, b1, b2, b3, b4, b5, b6, b7;

    // ---- warmup: EMA only, no stores. 128 rows = 16 batches w0..w15. ----
    // FIFO is pure loads: each WAITV(8) retires exactly the batch consumed
    // next. Final ALD8(a) prefetches main batch m0 -- no drain at boundary.
    if (nwarm) {
        ALD8(a);                            // w0
        for (int i = 0; i < 7; ++i) {
            ALD8(b); WAITV(8); EMA8(a);     // issue w(2i+1), consume w(2i)
            ALD8(a); WAITV(8); EMA8(b);     // issue w(2i+2), consume w(2i+1)
        }
        ALD8(b); WAITV(8); EMA8(a);         // issue w15, consume w14
        ALD8(a); WAITV(8); EMA8(b);         // issue m0!,  consume w15
    } else {
        ALD8(a);                            // m0
    }

    // ---- main: nb odd (25 or 15) batches, no remainder. FIFO walk:
    // prologue: [L(m0)] -> ALD8 -> [L(m0),L(m1)]; W8 covers m0.
    // steady:  [S(k-1),L(k+1)] -> ALD8 -> [.., L(k+2)]; W16 retires the
    //          2-phase-old stores + covers L(k+1). Never vmcnt(0) in-loop.
    ALD8(b); WAITV(8); OUT8(a);             // issue m1, out m0
    const int pairs = (nb - 3) / 2;         // 11 or 6
    for (int i = 0; i < pairs; ++i) {
        ALD8(a); WAITV(16); OUT8(b);
        ALD8(b); WAITV(16); OUT8(a);
    }
    ALD8(a); WAITV(16); OUT8(b);            // issue m(nb-1), out m(nb-2)
    WAITV(8); OUT8(a);                      // out m(nb-1); endpgm drains rest
}

extern "C" void kernel_launch(void* const* d_in, const int* in_sizes, int n_in,
                              void* d_out, int out_size, void* d_ws, size_t ws_size,
                              hipStream_t stream) {
    const float* x = (const float*)d_in[0];
    float* out = (float*)d_out;
    float* ws = (float*)d_ws;

    dim3 grid(NCH, B_);          // 256 blocks x 8 waves = 2048 waves, 8/CU
    dim3 block(512);
    specnorm_kernel<<<grid, block, 0, stream>>>(x, out, ws);
}

// Round 8
// 234.369 us; speedup vs baseline: 1.0684x; 1.0684x over previous
//
#include <hip/hip_runtime.h>
#include <math.h>

// SpecNorm: x[B,T,F,2] fp32 -> x * rsqrt(ema(|x|) + eps)
// EMA sequential in T; lookback reconstructs state (0.9^128 ~= 1.4e-6 rel
// error; threshold 0.129, measured absmax 0.0156 at LOOKBACK=128).
//
// R12: R5..R11 invariance table: 2.42-2.75 TB/s across streams
// {256,1024,2048}, waves/CU {4,8,16}, granule {512B,1KB}, MLP {1,8},
// stores {nt,cached}. Bytes minimal (FETCH==input, WRITE==output). m13's
// float4 copy hits 6.3 TB/s with the SAME 1 KB wave-granules -> granule
// and concurrency are not the limiter. Residual structural difference:
// instantaneous DRAM footprint. Copy sweeps ONE contiguous device-wide
// window (row-buffer hits); our T-serial EMA forces 256 scattered R+W
// streams (~15 MB instantaneous footprint > ~8 MB open-row capacity ->
// row thrash at ~0.4x streaming). Last in-topology knob: WAVE DRIFT --
// nothing bounds skew between a block's 4 waves (vmcnt is per-wave), so
// the nominal 32 KB contiguous block-burst decays into 4 independent
// strided 1 KB streams. This round: raw s_barrier per batch (after the
// load burst) to keep bursts tight. NOT __syncthreads() -- that drains
// vmcnt(0) and would kill the counted pipeline. Barrier count uniform
// within block; all 4 waves have live lanes (tid<=240) -> no deadlock.
// A/B vs R10: everything else byte-identical.
// Flat outcome => topology wall proven, declare roofline.

#define ALPHA 0.9f
#define OMA   0.1f
#define EPS_  1e-12f

// aligned(8): row base float-index is (b*2000+t)*962 == 2t mod 4, so odd
// rows give only 8 B alignment for the per-thread quad.
typedef float vf4 __attribute__((ext_vector_type(4), aligned(8)));
typedef float vf2 __attribute__((ext_vector_type(2), aligned(8)));

constexpr int B_ = 16, T_ = 2000, F_ = 481;
constexpr int NCH = 16, LOOKBACK = 128;
constexpr int OUT0 = 200, OUTN = 120;   // 200 + 15*120 = 2000; both %8 == 0
constexpr int ROWF = 2 * F_;            // 962 floats per row (3848 B)

#define SB() __builtin_amdgcn_sched_barrier(0)
#define SBAR() do { __builtin_amdgcn_s_barrier(); SB(); } while (0)
// Counted wait: N youngest vmem ops may remain outstanding. sched_barrier
// right after so dependent VALU can't be hoisted past it (rule #18).
#define WAITV(N) do { \
  asm volatile("s_waitcnt vmcnt(" #N ")" ::: "memory"); SB(); \
} while (0)

// Two rows from one pointer: offset imm is 13-bit signed, row stride
// 3848 B fits once. "=&v" earlyclobber: dest must not alias the addr pair.
#define ALD2(d0, d1, p) \
  asm volatile("global_load_dwordx4 %0, %2, off\n\t" \
               "global_load_dwordx4 %1, %2, off offset:3848" \
               : "=&v"(d0), "=&v"(d1) : "v"(p))

// 8-row batch: 8 loads issued back-to-back (MLP 8), pointers advance 8 rows.
// s_barrier after the burst: all 4 waves of the block issue their quarter of
// the 8-row 30 KB span within one tight window -> contiguous DRAM burst.
#define ALD8(V) do { \
  ALD2(V##0, V##1, p0); ALD2(V##2, V##3, p1); \
  ALD2(V##4, V##5, p2); ALD2(V##6, V##7, p3); \
  p0 += 8 * ROWF; p1 += 8 * ROWF; p2 += 8 * ROWF; p3 += 8 * ROWF; \
  SBAR(); \
} while (0)

#define EMA1(v) do { \
  float aA = __builtin_amdgcn_sqrtf((v).x * (v).x + (v).y * (v).y); \
  float aB = __builtin_amdgcn_sqrtf((v).z * (v).z + (v).w * (v).w); \
  sA = ALPHA * sA + OMA * aA; \
  sB = ALPHA * sB + OMA * aB; \
} while (0)

#define EMA8(V) do { EMA1(V##0); EMA1(V##1); EMA1(V##2); EMA1(V##3); \
                     EMA1(V##4); EMA1(V##5); EMA1(V##6); EMA1(V##7); } while (0)

// One output row: EMA update, rsqrt, one cached 16 B store per lane via asm
// (exact FIFO accounting). tid==240 stores only its valid 8 B A-half (16 B
// would clobber next row's f=0, owned by tid 0 of this block).
#define OUT1(v) do { \
  EMA1(v); \
  float iA = __builtin_amdgcn_rsqf(sA + EPS_); \
  float iB = __builtin_amdgcn_rsqf(sB + EPS_); \
  if (hasB) { \
    vf4 o = { (v).x * iA, (v).y * iA, (v).z * iB, (v).w * iB }; \
    asm volatile("global_store_dwordx4 %0, %1, off" :: "v"(op), "v"(o)); \
  } else { \
    vf2 o = { (v).x * iA, (v).y * iA }; \
    asm volatile("global_store_dwordx2 %0, %1, off" :: "v"(op), "v"(o)); \
  } \
  op += ROWF; \
} while (0)

#define OUT8(V) do { OUT1(V##0); OUT1(V##1); OUT1(V##2); OUT1(V##3); \
                     OUT1(V##4); OUT1(V##5); OUT1(V##6); OUT1(V##7); } while (0)

__global__ __launch_bounds__(256, 1)
void specnorm_kernel(const float* __restrict__ x, float* __restrict__ out,
                     float* __restrict__ ws) {
    const int tid = threadIdx.x;
    if (tid > 240) return;              // 241..255 idle; waves 0..3 all live
    const int chunk = blockIdx.x;
    const int b = blockIdx.y;
    const bool hasB = (tid < 240);      // tid==240 owns only f=480

    // s0[f] = 0.001 + f*step
    const float step = (float)((0.0001 - 0.001) / (double)(F_ - 1));
    float sA = 0.001f + (float)(2 * tid) * step;
    float sB = 0.001f + (float)(2 * tid + 1) * step;

    const int tout0 = (chunk == 0) ? 0 : OUT0 + (chunk - 1) * OUTN;
    const int nb    = (chunk == 0) ? (OUT0 / 8) : (OUTN / 8);  // 25 or 15
    const int nwarm = (chunk == 0) ? 0 : LOOKBACK;
    const int tstart = tout0 - nwarm;   // >= 72 for chunk >= 1 (OUT0>=LOOKBACK)

    // NOTE: tid==240's 16 B load reads 8 B past the row (= next row's f=0,
    // harmless). At the very last row of the buffer this over-reads 8 B past
    // the end; allocation is page-granular with ~2 KB slack (123,136,000 B
    // is not page-multiple), so the access stays mapped.
    const float* base = x + (size_t)(b * T_ + tstart) * ROWF + 4 * tid;
    const float* p0 = base;
    const float* p1 = base + 2 * ROWF;
    const float* p2 = base + 4 * ROWF;
    const float* p3 = base + 6 * ROWF;
    float* op = out + (size_t)(b * T_ + tout0) * ROWF + 4 * tid;
    (void)ws;

    vf4 a0, a1, a2, a3, a4, a5, a6, a7;
    vf4 b0, b1, b2, b3, b4, b5, b6, b7;

    // ---- warmup: EMA only, no stores. 128 rows = 16 batches w0..w15. ----
    // FIFO is pure loads: each WAITV(8) retires exactly the batch consumed
    // next. Final ALD8(a) prefetches main batch m0 -- no drain at boundary.
    if (nwarm) {
        ALD8(a);                            // w0
        for (int i = 0; i < 7; ++i) {
            ALD8(b); WAITV(8); EMA8(a);     // issue w(2i+1), consume w(2i)
            ALD8(a); WAITV(8); EMA8(b);     // issue w(2i+2), consume w(2i+1)
        }
        ALD8(b); WAITV(8); EMA8(a);         // issue w15, consume w14
        ALD8(a); WAITV(8); EMA8(b);         // issue m0!,  consume w15
    } else {
        ALD8(a);                            // m0
    }

    // ---- main: nb odd (25 or 15) batches, no remainder. FIFO walk:
    // prologue: [L(m0)] -> ALD8 -> [L(m0),L(m1)]; W8 covers m0.
    // steady:  [S(k-1),L(k+1)] -> ALD8 -> [.., L(k+2)]; W16 retires the
    //          2-phase-old stores + covers L(k+1). Never vmcnt(0) in-loop.
    ALD8(b); WAITV(8); OUT8(a);             // issue m1, out m0
    const int pairs = (nb - 3) / 2;         // 11 or 6
    for (int i = 0; i < pairs; ++i) {
        ALD8(a); WAITV(16); OUT8(b);
        ALD8(b); WAITV(16); OUT8(a);
    }
    ALD8(a); WAITV(16); OUT8(b);            // issue m(nb-1), out m(nb-2)
    WAITV(8); OUT8(a);                      // out m(nb-1); endpgm drains rest
}

extern "C" void kernel_launch(void* const* d_in, const int* in_sizes, int n_in,
                              void* d_out, int out_size, void* d_ws, size_t ws_size,
                              hipStream_t stream) {
    const float* x = (const float*)d_in[0];
    float* out = (float*)d_out;
    float* ws = (float*)d_ws;

    dim3 grid(NCH, B_);          // 256 blocks x 4 waves = 1024 waves
    dim3 block(256);
    specnorm_kernel<<<grid, block, 0, stream>>>(x, out, ws);
}

// Round 9
// 232.791 us; speedup vs baseline: 1.0757x; 1.0068x over previous
//
#include <hip/hip_runtime.h>
#include <math.h>

// SpecNorm: x[B,T,F,2] fp32 -> x * rsqrt(ema(|x|) + eps)
// EMA sequential in T; lookback reconstructs state (0.9^128 ~= 1.4e-6 rel
// error; threshold 0.129, measured absmax 0.0156 at LOOKBACK=128).
//
// R13: R12's s_barrier burst-alignment gave the first positive signal in 5
// rounds (92.8 -> 89.3 us): burst coherence matters -> the limiter is
// per-channel R/W turnaround on 512 interleaved streams (copy=6.3 TB/s has
// 2 device-wide streams; we sit at 2.7). This round scales the lever:
// 16-row (60 KB) coherent load bursts + 16-row store bursts via FOUR 8-row
// register buffers (a,b,c,d), barrier-aligned, same byte-minimal geometry.
// FIFO (8-op units, L=loads S=stores, vmcnt semantics: wait retires oldest):
//   pro:    [L0] -> +L1,L2,L3 -> W16 retires L0,L1 -> S0,S1 -> [L2,L3,S0,S1]
//   steady: +L,L -> 64 outstanding -> W32 retires {2-step-old S pair, L pair
//           we consume} -> OUT pair -> [S,S,L,L,S,S]=48. Never drains young
//           stores; never vmcnt(0) in-loop.
//   tails (nb=25 / nb=15 peeled explicitly): single-issue steps use W24
//   (retires 32 incl. the consumed L pair) and final W16 (retires 24 incl.
//   the last L) -- all consumed loads are in the retired-oldest set, no
//   reliance on OOO completion.
// Pre-commitment: flat result (+-3%) => scattered-stream R/W-mix ceiling
// proven by exhaustion (streams/waves/granule/MLP/store-type/burst 8->16),
// declare roofline.

#define ALPHA 0.9f
#define OMA   0.1f
#define EPS_  1e-12f

// aligned(8): row base float-index is (b*2000+t)*962 == 2t mod 4, so odd
// rows give only 8 B alignment for the per-thread quad.
typedef float vf4 __attribute__((ext_vector_type(4), aligned(8)));
typedef float vf2 __attribute__((ext_vector_type(2), aligned(8)));

constexpr int B_ = 16, T_ = 2000, F_ = 481;
constexpr int NCH = 16, LOOKBACK = 128;
constexpr int OUT0 = 200, OUTN = 120;   // 200 + 15*120 = 2000; nb = 25 / 15
constexpr int ROWF = 2 * F_;            // 962 floats per row (3848 B)

#define SB() __builtin_amdgcn_sched_barrier(0)
#define SBAR() do { __builtin_amdgcn_s_barrier(); SB(); } while (0)
// Counted wait: N youngest vmem ops may remain outstanding. sched_barrier
// right after so dependent VALU can't be hoisted past it (rule #18).
#define WAITV(N) do { \
  asm volatile("s_waitcnt vmcnt(" #N ")" ::: "memory"); SB(); \
} while (0)

// Two rows from one pointer: offset imm is 13-bit signed, row stride
// 3848 B fits once. "=&v" earlyclobber: dest must not alias the addr pair.
#define ALD2(d0, d1, p) \
  asm volatile("global_load_dwordx4 %0, %2, off\n\t" \
               "global_load_dwordx4 %1, %2, off offset:3848" \
               : "=&v"(d0), "=&v"(d1) : "v"(p))

// 8-row batch: 8 loads back-to-back, pointers advance 8 rows, barrier keeps
// the block's 4 waves' quarter-bursts in one tight window (R12: +4%).
#define ALD8(V) do { \
  ALD2(V##0, V##1, p0); ALD2(V##2, V##3, p1); \
  ALD2(V##4, V##5, p2); ALD2(V##6, V##7, p3); \
  p0 += 8 * ROWF; p1 += 8 * ROWF; p2 += 8 * ROWF; p3 += 8 * ROWF; \
  SBAR(); \
} while (0)

#define EMA1(v) do { \
  float aA = __builtin_amdgcn_sqrtf((v).x * (v).x + (v).y * (v).y); \
  float aB = __builtin_amdgcn_sqrtf((v).z * (v).z + (v).w * (v).w); \
  sA = ALPHA * sA + OMA * aA; \
  sB = ALPHA * sB + OMA * aB; \
} while (0)

#define EMA8(V) do { EMA1(V##0); EMA1(V##1); EMA1(V##2); EMA1(V##3); \
                     EMA1(V##4); EMA1(V##5); EMA1(V##6); EMA1(V##7); } while (0)

// One output row: EMA update, rsqrt, one cached 16 B store per lane via asm.
// tid==240 stores only its valid 8 B A-half (16 B would clobber next row's
// f=0, owned by tid 0 of this block). Store data regs are read at issue;
// reloading a buffer whose stores are still outstanding is safe.
#define OUT1(v) do { \
  EMA1(v); \
  float iA = __builtin_amdgcn_rsqf(sA + EPS_); \
  float iB = __builtin_amdgcn_rsqf(sB + EPS_); \
  if (hasB) { \
    vf4 o = { (v).x * iA, (v).y * iA, (v).z * iB, (v).w * iB }; \
    asm volatile("global_store_dwordx4 %0, %1, off" :: "v"(op), "v"(o)); \
  } else { \
    vf2 o = { (v).x * iA, (v).y * iA }; \
    asm volatile("global_store_dwordx2 %0, %1, off" :: "v"(op), "v"(o)); \
  } \
  op += ROWF; \
} while (0)

#define OUT8(V) do { OUT1(V##0); OUT1(V##1); OUT1(V##2); OUT1(V##3); \
                     OUT1(V##4); OUT1(V##5); OUT1(V##6); OUT1(V##7); } while (0)

__global__ __launch_bounds__(256, 1)
void specnorm_kernel(const float* __restrict__ x, float* __restrict__ out,
                     float* __restrict__ ws) {
    const int tid = threadIdx.x;
    if (tid > 240) return;          // lanes 241..255 of wave 3 exit; all 4
                                    // waves keep live lanes -> barriers safe
    const int chunk = blockIdx.x;
    const int b = blockIdx.y;
    const bool hasB = (tid < 240);      // tid==240 owns only f=480

    // s0[f] = 0.001 + f*step
    const float step = (float)((0.0001 - 0.001) / (double)(F_ - 1));
    float sA = 0.001f + (float)(2 * tid) * step;
    float sB = 0.001f + (float)(2 * tid + 1) * step;

    const int tout0 = (chunk == 0) ? 0 : OUT0 + (chunk - 1) * OUTN;
    const int nwarm = (chunk == 0) ? 0 : LOOKBACK;
    const int tstart = tout0 - nwarm;   // >= 72 for chunk >= 1 (OUT0>=LOOKBACK)

    // NOTE: tid==240's 16 B load reads 8 B past the row (= next row's f=0,
    // harmless). At the very last row of the buffer this over-reads 8 B past
    // the end; allocation is page-granular with ~2 KB slack (123,136,000 B
    // is not page-multiple), so the access stays mapped.
    const float* base = x + (size_t)(b * T_ + tstart) * ROWF + 4 * tid;
    const float* p0 = base;
    const float* p1 = base + 2 * ROWF;
    const float* p2 = base + 4 * ROWF;
    const float* p3 = base + 6 * ROWF;
    float* op = out + (size_t)(b * T_ + tout0) * ROWF + 4 * tid;
    (void)ws;

    vf4 a0, a1, a2, a3, a4, a5, a6, a7;
    vf4 b0, b1, b2, b3, b4, b5, b6, b7;
    vf4 c0, c1, c2, c3, c4, c5, c6, c7;
    vf4 d0, d1, d2, d3, d4, d5, d6, d7;

    // ---- warmup: EMA only, no stores. 128 rows = 16 batches w0..w15, two
    // buffers (a,b). Pure-load FIFO: each WAITV(8) retires the consumed
    // batch. Final ALD8(a) prefetches main batch m0 -- no boundary drain.
    if (nwarm) {
        ALD8(a);                            // w0
        for (int i = 0; i < 7; ++i) {
            ALD8(b); WAITV(8); EMA8(a);     // issue w(2i+1), consume w(2i)
            ALD8(a); WAITV(8); EMA8(b);     // issue w(2i+2), consume w(2i+1)
        }
        ALD8(b); WAITV(8); EMA8(a);         // issue w15, consume w14
        ALD8(a); WAITV(8); EMA8(b);         // issue m0!,  consume w15
    } else {
        ALD8(a);                            // m0
    }
    // entering main: [L(m0)] = 8 outstanding, m0 in a.

    // ---- main: 16-row load bursts / 16-row store bursts, 4-buffer rotation.
    // pro: issue m1,m2,m3; consume (m0,m1).
    ALD8(b); ALD8(c); ALD8(d);              // [L0,L1,L2,L3] = 32
    WAITV(16);                              // retires L0,L1
    SBAR(); OUT8(a); OUT8(b);               // [L2,L3,S0,S1] = 32

    // double-iters: each half issues a 16-row burst, consumes the 2-batch-old
    // pair. W32 retires exactly {2-step-old store pair, consumed load pair}.
    const int D = (chunk == 0) ? 5 : 2;     // nb = 25 -> pro+5*4+... ; 15 -> pro+2*4+...
    for (int i = 0; i < D; ++i) {
        ALD8(a); ALD8(b); WAITV(32); SBAR(); OUT8(c); OUT8(d);
        ALD8(c); ALD8(d); WAITV(32); SBAR(); OUT8(a); OUT8(b);
    }

    if (chunk == 0) {
        // consumed so far: m0..m21; issued: m0..m23. One batch (m24) left.
        ALD8(a);                            // 56 out
        WAITV(24);                          // retires S18,S19,L22,L23
        SBAR(); OUT8(c); OUT8(d);           // [S20,S21,L24,S22,S23] = 40
        WAITV(16);                          // retires S20,S21,L24 (L24 covered)
        SBAR(); OUT8(a);                    // m24; endpgm drains rest
    } else {
        // consumed so far: m0..m9; issued: m0..m11. m12..m14 left.
        ALD8(a); ALD8(b); WAITV(32); SBAR(); OUT8(c); OUT8(d);   // m10,m11
        ALD8(c);                            // m14; 56 out
        WAITV(24);                          // retires S8,S9,L12,L13
        SBAR(); OUT8(a); OUT8(b);           // m12,m13; [S10,S11,L14,S12,S13]=40
        WAITV(16);                          // retires S10,S11,L14 (L14 covered)
        SBAR(); OUT8(c);                    // m14; endpgm drains rest
    }
}

extern "C" void kernel_launch(void* const* d_in, const int* in_sizes, int n_in,
                              void* d_out, int out_size, void* d_ws, size_t ws_size,
                              hipStream_t stream) {
    const float* x = (const float*)d_in[0];
    float* out = (float*)d_out;
    float* ws = (float*)d_ws;

    dim3 grid(NCH, B_);          // 256 blocks x 4 waves = 1024 waves
    dim3 block(256);
    specnorm_kernel<<<grid, block, 0, stream>>>(x, out, ws);
}